// Round 6
// baseline (564.899 us; speedup 1.0000x reference)
//
#include <hip/hip_runtime.h>
#include <math.h>

#define NC 21
#define NB 8
#define HW (512*512)
#define EPS 1e-8f
#define NREP 4
#define TPB 256
#define CHUNK4 128                        // float4 per plane per chunk (2 KB)
#define CHUNKS_PER_BLK 4
#define BLK4 (CHUNK4 * CHUNKS_PER_BLK)    // 512 float4 per block
#define TILES_PER_IMG ((HW/4) / BLK4)     // 128
#define NBLK (NB * TILES_PER_IMG)         // 1024
#define PSTRIDE 512

typedef float f32x4 __attribute__((ext_vector_type(4)));

// Round-7: global_load_lds (direct-to-LDS DMA) staging.
// Evidence chain: (a) dur invariant 240-275us across VGPR 24-52, occ 31-57%,
// channel-major vs plane-major vs rotated -- only nt moved it (-12%);
// (b) THIS round's replay rows: L3-resident passes (FETCH~0) run at 247.8us
// vs cold 250.9us -- duration independent of memory source; (c) Little's law:
// ~1 outstanding wave-load per CU despite 10+ resident waves. => the cap is
// the CU's vector-load RETURN path (VGPR writeback/dependency tracking).
// global_load_lds bypasses VGPR return entirely (LDS-DMA, vmcnt-tracked):
// 42 x 1KB staged per chunk with zero register pressure, one latency per
// batch instead of one per load. Compiler never auto-emits it (guide CM#1).
// LDS dest rule honored: wave-uniform base, HW adds lane*16 (m104/m108);
// per-lane GLOBAL address supplies the data. Linear layout, no swizzle.

#define UPD(val, cc, mm, jj) \
    if ((val) > (mm) || ((val) == (mm) && (cc) < (jj))) { (mm) = (val); (jj) = (cc); }

__device__ __forceinline__ void stage_plane(const f32x4* gsrc, f32x4* lds_uniform, int lane) {
    // 128 float4 = 2 wave-instructions of (64 lanes x 16 B)
    __builtin_amdgcn_global_load_lds(
        (const __attribute__((address_space(1))) void*)(gsrc + lane),
        (__attribute__((address_space(3))) void*)(uintptr_t)lds_uniform,
        16, 0, 0);
    __builtin_amdgcn_global_load_lds(
        (const __attribute__((address_space(1))) void*)(gsrc + 64 + lane),
        (__attribute__((address_space(3))) void*)(uintptr_t)(lds_uniform + 64),
        16, 0, 0);
}

template <bool PARTIAL>
__global__ __launch_bounds__(TPB) void cm_accum(const float* __restrict__ input,
                                                const float* __restrict__ target,
                                                float* __restrict__ cm /*[NB][NC][NC]*/,
                                                float* __restrict__ partial /*[NBLK][PSTRIDE]*/) {
    __shared__ f32x4 stage[NC][CHUNK4];        // 42 KB staging buffer
    __shared__ float scm[NREP][NC * NC];       // 7 KB confusion tiles
    const int t = threadIdx.x;
    const int wave = t >> 6, lane = t & 63;
    for (int i = t; i < NREP * NC * NC; i += TPB) ((float*)scm)[i] = 0.0f;

    const int bid  = blockIdx.x;
    const int b    = bid / TILES_PER_IMG;
    const int tile = bid % TILES_PER_IMG;
    const f32x4* ip = (const f32x4*)(input  + (size_t)b * NC * HW);
    const f32x4* tp = (const f32x4*)(target + (size_t)b * NC * HW);
    const int plane4 = HW / 4;

    for (int ch = 0; ch < CHUNKS_PER_BLK; ++ch) {
        const int q0 = tile * BLK4 + ch * CHUNK4;

        // ---- stage all 21 input plane-chunks via LDS-DMA (42 x 1KB in flight) ----
        for (int c = wave; c < NC; c += 4)
            stage_plane(ip + (size_t)c * plane4 + q0, &stage[c][0], lane);
        asm volatile("s_waitcnt vmcnt(0)" ::: "memory");
        __syncthreads();

        // ---- argmax from LDS: thread t owns float2 #t (ds_read_b64, 2-way=free) ----
        float m0 = -INFINITY, m1 = -INFINITY;
        int j0 = NC, j1 = NC;
        #pragma unroll
        for (int c = 0; c < NC; ++c) {
            const float* s = (const float*)&stage[c][0];
            const float v0 = s[2 * t], v1 = s[2 * t + 1];
            UPD(v0, c, m0, j0);
            UPD(v1, c, m1, j1);
        }
        __syncthreads();   // all reads done before re-staging overwrites

        // ---- stage all 21 target plane-chunks ----
        for (int c = wave; c < NC; c += 4)
            stage_plane(tp + (size_t)c * plane4 + q0, &stage[c][0], lane);
        asm volatile("s_waitcnt vmcnt(0)" ::: "memory");
        __syncthreads();

        // ---- scatter target mass into replicated LDS cm tiles ----
        float* my = scm[t & (NREP - 1)];
        #pragma unroll
        for (int c = 0; c < NC; ++c) {
            const float* s = (const float*)&stage[c][0];
            atomicAdd(&my[c * NC + j0], s[2 * t]);
            atomicAdd(&my[c * NC + j1], s[2 * t + 1]);
        }
        __syncthreads();   // before next chunk overwrites stage
    }

    if (PARTIAL) {
        // contention-free flush to this block's own slice
        float* pout = partial + (size_t)bid * PSTRIDE;
        for (int i = t; i < PSTRIDE; i += TPB) {
            float s = 0.0f;
            if (i < NC * NC) {
                #pragma unroll
                for (int r = 0; r < NREP; ++r) s += scm[r][i];
            }
            pout[i] = s;   // pad region written as 0 -> reduce needs no guards
        }
    } else {
        for (int i = t; i < NC * NC; i += TPB) {
            float s = 0.0f;
            #pragma unroll
            for (int r = 0; r < NREP; ++r) s += scm[r][i];
            atomicAdd(&cm[b * NC * NC + i], s);
        }
    }
}

// partial[b*TILES_PER_IMG + s][e] summed over s -> cm[b][e]. 8 blocks.
__global__ __launch_bounds__(256) void cm_reduce(const float* __restrict__ partial,
                                                 float* __restrict__ cm) {
    const int b = blockIdx.x, t = threadIdx.x;
    const float* p = partial + (size_t)b * TILES_PER_IMG * PSTRIDE;
    float s0 = 0.0f, s1 = 0.0f;
    #pragma unroll 8
    for (int s = 0; s < TILES_PER_IMG; ++s) {
        s0 += p[(size_t)s * PSTRIDE + t];
        s1 += p[(size_t)s * PSTRIDE + t + 256];
    }
    cm[b * NC * NC + t] = s0;
    if (t + 256 < NC * NC) cm[b * NC * NC + t + 256] = s1;
}

// rowsum[b,i] = sum_j cm[b,i,j]; out[i,j] = mean_b cm[b,i,j]/(rowsum[b,i]+EPS)
__global__ __launch_bounds__(512) void cm_final(const float* __restrict__ cm,
                                                float* __restrict__ out) {
    __shared__ float rs[NB * NC];
    const int t = threadIdx.x;
    if (t < NB * NC) {
        const int b = t / NC, i = t % NC;
        float s = 0.0f;
        for (int j = 0; j < NC; ++j) s += cm[b * NC * NC + i * NC + j];
        rs[t] = s + EPS;
    }
    __syncthreads();
    if (t < NC * NC) {
        const int i = t / NC;
        float acc = 0.0f;
        for (int b = 0; b < NB; ++b) acc += cm[b * NC * NC + t] / rs[b * NC + i];
        out[t] = acc * (1.0f / NB);
    }
}

extern "C" void kernel_launch(void* const* d_in, const int* in_sizes, int n_in,
                              void* d_out, int out_size, void* d_ws, size_t ws_size,
                              hipStream_t stream) {
    const float* input  = (const float*)d_in[0];
    const float* target = (const float*)d_in[1];
    float* out = (float*)d_out;

    const size_t partial_floats = (size_t)NBLK * PSTRIDE;   // 512K floats = 2 MB
    const size_t need = (partial_floats + NB * NC * NC) * sizeof(float);

    if (ws_size >= need) {
        float* partial = (float*)d_ws;
        float* cm      = partial + partial_floats;
        cm_accum<true><<<NBLK, TPB, 0, stream>>>(input, target, cm, partial);
        cm_reduce<<<NB, 256, 0, stream>>>(partial, cm);
        cm_final<<<1, 512, 0, stream>>>(cm, out);
    } else {
        float* cm = (float*)d_ws;   // NB*NC*NC floats
        hipMemsetAsync(cm, 0, NB * NC * NC * sizeof(float), stream);
        cm_accum<false><<<NBLK, TPB, 0, stream>>>(input, target, cm, nullptr);
        cm_final<<<1, 512, 0, stream>>>(cm, out);
    }
}